// Round 5
// baseline (180.203 us; speedup 1.0000x reference)
//
#include <hip/hip_runtime.h>
#include <math.h>

#define W 512
#define H 512
#define NUM_R 725
#define NUM_T 180
#define RCHUNK 64   // sweep-rows per block; grid (180, 512/64) = 1440 blocks

// ---------------------------------------------------------------------------
// Transpose 512x512 f32: imgT[n*W + x] = img[x*W + n]
// ---------------------------------------------------------------------------
__global__ __launch_bounds__(256) void transpose_k(const float* __restrict__ in,
                                                   float* __restrict__ out) {
    __shared__ float tile[32][33];
    const int bx = blockIdx.x * 32, by = blockIdx.y * 32;
    const int tx = threadIdx.x, ty = threadIdx.y;  // block (32, 8)
#pragma unroll
    for (int j = 0; j < 32; j += 8)
        tile[ty + j][tx] = in[(size_t)(by + ty + j) * W + (bx + tx)];
    __syncthreads();
#pragma unroll
    for (int j = 0; j < 32; j += 8)
        out[(size_t)(bx + ty + j) * H + (by + tx)] = tile[tx][ty + j];
}

// ---------------------------------------------------------------------------
// Scatter Hough, lane axis = sweep axis (the max(|s|,|c|) coefficient axis).
// Pixel (i,j) hits bin r iff |u - r| <= hw,  u = (i*c + j*s + diag)/step,
// hw = max(|s|,|c|)/(2*step)  — exactly equivalent to the reference's
// round() membership for both sweep branches.
//   x-sweep (|s|>=|c|): lanes along j (img rows),  lane du = s/step
//   y-sweep (|c|> |s|): lanes along i (imgT rows), lane du = c/step
// => |lane du| in [0.345, 0.488] for ALL thetas; hit window = |du| so each
// rho bin gets ~1 hit per pixel run: no same-address LDS atomic contention,
// and hitting lanes map to consecutive r (distinct banks).
// u tracked in Q32, advanced by loop_co per staged row (refresh per block).
// ---------------------------------------------------------------------------
__global__ __launch_bounds__(256) void hough_scatter_k(const float* __restrict__ img,
                                                       const float* __restrict__ imgT,
                                                       float* __restrict__ out,
                                                       int hasT) {
    const int t   = blockIdx.x;            // theta 0..179
    const int n0  = blockIdx.y * RCHUNK;   // sweep-row chunk base
    const int tid = threadIdx.x;

    __shared__ float racc[768];            // 725 rho bins (padded)
    racc[tid] = 0.f;
    racc[tid + 256] = 0.f;
    racc[tid + 512] = 0.f;
    __syncthreads();

    // ---- per-theta constants (f64, same trig path validated R1-R4) ----
    const double theta = (double)t * (M_PI / 180.0);
    const double s = sin(theta);
    const double c = cos(theta);
    const bool use_x = fabs(s) >= fabs(c);
    const double diag = sqrt(524288.0);          // sqrt(W*W + H*H)
    const double step = (2.0 * diag) / 724.0;    // np.linspace step
    const double inv_step = 1.0 / step;

    const double lane_co = (use_x ? s : c) * inv_step;  // du per pixel (lane axis)
    const double loop_co = (use_x ? c : s) * inv_step;  // du per staged row
    const double dstep   = diag * inv_step;

    const double SC = 4294967296.0;              // 2^32
    const long long lq = (long long)rint(loop_co * SC);
    const double hw = fabs(lane_co) * 0.5;       // in [0.172, 0.244]
    const unsigned hwq = (unsigned)(hw * SC);
    const unsigned A = 0x80000000u - hwq;        // hit iff lo32 - A <= B
    const unsigned B = 2u * hwq;

    // ---- this thread's two lane-axis pixels ----
    const int p0 = 2 * tid;
    const double rowpart = (double)n0 * loop_co + dstep;
    long long u1 = (long long)rint((rowpart + (double)p0 * lane_co) * SC) + (1ll << 31);
    long long u2 = (long long)rint((rowpart + (double)(p0 + 1) * lane_co) * SC) + (1ll << 31);

    if (use_x || hasT) {
        const float* __restrict__ base = use_x ? img : imgT;
        const float2* rowp = (const float2*)(base + (size_t)n0 * W) + tid;
#pragma unroll 8
        for (int j = 0; j < RCHUNK; ++j) {
            const float2 v = rowp[j * (W / 2)];
            const unsigned F1 = (unsigned)u1;
            const unsigned F2 = (unsigned)u2;
            const int r1 = (int)(u1 >> 32);
            const int r2 = (int)(u2 >> 32);
            u1 += lq;
            u2 += lq;
            if (F1 - A <= B) atomicAdd(&racc[r1], v.x);
            if (F2 - A <= B) atomicAdd(&racc[r2], v.y);
        }
    } else {
        // fallback (no workspace): y-sweep via strided column reads of img
        for (int j = 0; j < RCHUNK; ++j) {
            const float vx = img[(size_t)p0 * W + (n0 + j)];
            const float vy = img[(size_t)(p0 + 1) * W + (n0 + j)];
            const unsigned F1 = (unsigned)u1;
            const unsigned F2 = (unsigned)u2;
            const int r1 = (int)(u1 >> 32);
            const int r2 = (int)(u2 >> 32);
            u1 += lq;
            u2 += lq;
            if (F1 - A <= B) atomicAdd(&racc[r1], vx);
            if (F2 - A <= B) atomicAdd(&racc[r2], vy);
        }
    }

    __syncthreads();

    // ---- flush partial accumulators to global (out pre-zeroed) ----
#pragma unroll
    for (int k = 0; k < 3; ++k) {
        const int r = tid + 256 * k;
        if (r < NUM_R) atomicAdd(&out[(size_t)r * NUM_T + t], racc[r]);
    }
}

extern "C" void kernel_launch(void* const* d_in, const int* in_sizes, int n_in,
                              void* d_out, int out_size, void* d_ws, size_t ws_size,
                              hipStream_t stream) {
    const float* img = (const float*)d_in[0];
    float* out = (float*)d_out;

    // out is poisoned before every timed call; zero it (atomic accumulation).
    hipMemsetAsync(d_out, 0, (size_t)NUM_R * NUM_T * sizeof(float), stream);

    const int hasT = (ws_size >= (size_t)W * H * sizeof(float)) ? 1 : 0;
    float* imgT = (float*)d_ws;
    if (hasT) {
        transpose_k<<<dim3(16, 16), dim3(32, 8), 0, stream>>>(img, imgT);
    }

    hough_scatter_k<<<dim3(NUM_T, H / RCHUNK), dim3(256), 0, stream>>>(
        img, hasT ? imgT : img, out, hasT);
}

// Round 6
// 85.108 us; speedup vs baseline: 2.1173x; 2.1173x over previous
//
#include <hip/hip_runtime.h>
#include <math.h>

#define W 512
#define H 512
#define NUM_R 725
#define NUM_T 180
#define RCHUNK 64               // sweep-rows per block
#define NCHUNK (H / RCHUNK)     // 8
#define RPAD 768                // padded rho bins

// ws layout: [0, W*H) floats = imgT ; then NCHUNK*NUM_T*RPAD floats = partials
#define WS_FLOATS ((size_t)W * H + (size_t)NCHUNK * NUM_T * RPAD)

// ---------------------------------------------------------------------------
// Transpose 512x512 f32: imgT[a*H + b] = img[b*W + a]
// ---------------------------------------------------------------------------
__global__ __launch_bounds__(256) void transpose_k(const float* __restrict__ in,
                                                   float* __restrict__ out) {
    __shared__ float tile[32][33];
    const int bx = blockIdx.x * 32, by = blockIdx.y * 32;
    const int tx = threadIdx.x, ty = threadIdx.y;  // block (32, 8)
#pragma unroll
    for (int j = 0; j < 32; j += 8)
        tile[ty + j][tx] = in[(size_t)(by + ty + j) * W + (bx + tx)];
    __syncthreads();
#pragma unroll
    for (int j = 0; j < 32; j += 8)
        out[(size_t)(bx + ty + j) * H + (by + tx)] = tile[tx][ty + j];
}

// ---------------------------------------------------------------------------
// Scatter Hough, ZERO atomics.
// Lane axis = max(|s|,|c|) axis => per wave-iteration, active lanes hit
// DISTINCT bins (hit window exactly tiles u-space at lane spacing), and each
// wave owns a private LDS accumulator array => plain ds_read/add/ds_write.
// Partials flushed non-atomically to ws; reduce_k sums the 8 chunks.
// Hit test: |u - r| <= hw, u = (i*c + j*s + diag)/step, hw = max|s|,|c|/(2step)
// — algebraically identical to the reference's round() membership (both
// sweep branches); Q32 incremental u (validated R4/R5: absmax 2.0).
// ---------------------------------------------------------------------------
__global__ __launch_bounds__(256) void hough_scatter_k(const float* __restrict__ img,
                                                       const float* __restrict__ imgT,
                                                       float* __restrict__ partial) {
    const int t   = blockIdx.x;            // theta 0..179
    const int n0  = blockIdx.y * RCHUNK;   // sweep-row chunk base
    const int tid = threadIdx.x;
    const int wave = tid >> 6;

    __shared__ float racc[4 * RPAD];       // per-wave private accumulators (12 KB)

    // zero accumulators (float4 vectorized: 768 float4 total)
    {
        float4* z = (float4*)racc;
#pragma unroll
        for (int k = 0; k < 3; ++k)
            z[tid + 256 * k] = make_float4(0.f, 0.f, 0.f, 0.f);
    }
    __syncthreads();

    // ---- per-theta constants (f64, same trig path validated R1-R5) ----
    const double theta = (double)t * (M_PI / 180.0);
    const double s = sin(theta);
    const double c = cos(theta);
    const bool use_x = fabs(s) >= fabs(c);
    const double diag = sqrt(524288.0);          // sqrt(W*W + H*H)
    const double step = (2.0 * diag) / 724.0;    // np.linspace step
    const double inv_step = 1.0 / step;

    const double lane_co = (use_x ? s : c) * inv_step;  // du per pixel (lane axis)
    const double loop_co = (use_x ? c : s) * inv_step;  // du per sweep row
    const double dstep   = diag * inv_step;

    const double SC = 4294967296.0;              // 2^32
    const long long lq = (long long)rint(loop_co * SC);
    const unsigned hwq = (unsigned)(fabs(lane_co) * 0.5 * SC);
    const unsigned A = 0x80000000u - hwq;        // hit iff lo32 - A <= B
    const unsigned B = 2u * hwq;

    // ---- this thread's two lane-axis pixels ----
    const int p0 = 2 * tid;
    const double rowpart = (double)n0 * loop_co + dstep;
    long long u1 = (long long)rint((rowpart + (double)p0 * lane_co) * SC) + (1ll << 31);
    long long u2 = (long long)rint((rowpart + (double)(p0 + 1) * lane_co) * SC) + (1ll << 31);

    float* racc_w = racc + wave * RPAD;
    const float* __restrict__ base = use_x ? img : imgT;
    const float2* rowp = (const float2*)(base + (size_t)n0 * W) + tid;

#pragma unroll 8
    for (int j = 0; j < RCHUNK; ++j) {
        const float2 v = rowp[j * (W / 2)];
        const unsigned F1 = (unsigned)u1;
        const unsigned F2 = (unsigned)u2;
        const int r1 = (int)(u1 >> 32);
        const int r2 = (int)(u2 >> 32);
        u1 += lq;
        u2 += lq;
        // r1,r2 always in [0,724] (|n*c+j*s| <= 511*sqrt2 < diag); distinct
        // bins across active lanes of this wave => non-atomic RMW is race-free.
        if (F1 - A <= B) racc_w[r1] += v.x;
        if (F2 - A <= B) racc_w[r2] += v.y;
    }

    __syncthreads();

    // ---- non-atomic flush: partial[chunk][t][r] (coalesced) ----
    float* dst = partial + ((size_t)blockIdx.y * NUM_T + t) * RPAD;
#pragma unroll
    for (int k = 0; k < 3; ++k) {
        const int r = tid + 256 * k;
        dst[r] = racc[r] + racc[RPAD + r] + racc[2 * RPAD + r] + racc[3 * RPAD + r];
    }
}

// ---------------------------------------------------------------------------
// Sum the NCHUNK partials into out[r*NUM_T + t]. Block = one theta.
// ---------------------------------------------------------------------------
__global__ __launch_bounds__(256) void reduce_k(const float* __restrict__ partial,
                                                float* __restrict__ out) {
    const int t = blockIdx.x;
    const int tid = threadIdx.x;
#pragma unroll
    for (int k = 0; k < 3; ++k) {
        const int r = tid + 256 * k;
        if (r < NUM_R) {
            float acc = 0.f;
#pragma unroll
            for (int ch = 0; ch < NCHUNK; ++ch)
                acc += partial[((size_t)ch * NUM_T + t) * RPAD + r];
            out[(size_t)r * NUM_T + t] = acc;
        }
    }
}

// ---------------------------------------------------------------------------
// Fallback (ws too small): R3's pure-gather kernel, no ws, no atomics.
// ---------------------------------------------------------------------------
__global__ __launch_bounds__(256) void hough_gather_k(const float* __restrict__ img,
                                                      float* __restrict__ out) {
    const int t = blockIdx.x;
    const int r = blockIdx.y * 256 + threadIdx.x;
    const int rc = (r < NUM_R) ? r : (NUM_R - 1);

    const double theta = (double)t * (M_PI / 180.0);
    const double s = sin(theta);
    const double c = cos(theta);
    const bool use_x = fabs(s) >= fabs(c);
    double dd = use_x ? s : c;
    if (fabs(dd) < 1e-6) dd = 1.0;
    const double a = use_x ? c : s;
    const double inv = 1.0 / dd;
    const double nk2 = -(a * inv);
    const double diag = sqrt(524288.0);
    const double step = (2.0 * diag) / 724.0;
    double rho = (double)rc * step - diag;
    if (rc == NUM_R - 1) rho = diag;

    const double SCALE = 1099511627776.0;  // 2^40
    const long long NK2q = (long long)rint(nk2 * SCALE);
    long long Y = (long long)rint(rho * inv * SCALE) + (1ll << 39);

    float acc = 0.f;
    if (use_x) {
#pragma unroll 8
        for (int n = 0; n < W; ++n) {
            const int y = (int)(Y >> 40);
            Y += NK2q;
            const float v = img[n * W + min(max(y, 0), W - 1)];
            acc += ((unsigned)y < (unsigned)W) ? v : 0.f;
        }
    } else {
#pragma unroll 4
        for (int n = 0; n < W; ++n) {
            const int y = (int)(Y >> 40);
            Y += NK2q;
            const float v = img[min(max(y, 0), W - 1) * W + n];
            acc += ((unsigned)y < (unsigned)W) ? v : 0.f;
        }
    }
    if (r < NUM_R) out[(size_t)r * NUM_T + t] = acc;
}

extern "C" void kernel_launch(void* const* d_in, const int* in_sizes, int n_in,
                              void* d_out, int out_size, void* d_ws, size_t ws_size,
                              hipStream_t stream) {
    const float* img = (const float*)d_in[0];
    float* out = (float*)d_out;

    if (ws_size >= WS_FLOATS * sizeof(float)) {
        float* imgT = (float*)d_ws;
        float* partial = (float*)d_ws + (size_t)W * H;

        transpose_k<<<dim3(16, 16), dim3(32, 8), 0, stream>>>(img, imgT);
        hough_scatter_k<<<dim3(NUM_T, NCHUNK), dim3(256), 0, stream>>>(img, imgT, partial);
        reduce_k<<<dim3(NUM_T), dim3(256), 0, stream>>>(partial, out);
    } else {
        hough_gather_k<<<dim3(NUM_T, (NUM_R + 255) / 256), dim3(256), 0, stream>>>(img, out);
    }
}

// Round 7
// 81.357 us; speedup vs baseline: 2.2150x; 1.0461x over previous
//
#include <hip/hip_runtime.h>
#include <math.h>

#define W 512
#define H 512
#define NUM_R 725
#define NUM_T 180
#define RCHUNK 64               // sweep-rows per block
#define NCHUNK (H / RCHUNK)     // 8
#define RPAD 768                // padded rho bins

// ws layout: [0, W*H) floats = imgT ; then NCHUNK*NUM_T*RPAD floats = partials
#define WS_FLOATS ((size_t)W * H + (size_t)NCHUNK * NUM_T * RPAD)

// ---------------------------------------------------------------------------
// Transpose 512x512 f32: imgT[a*H + b] = img[b*W + a]
// ---------------------------------------------------------------------------
__global__ __launch_bounds__(256) void transpose_k(const float* __restrict__ in,
                                                   float* __restrict__ out) {
    __shared__ float tile[32][33];
    const int bx = blockIdx.x * 32, by = blockIdx.y * 32;
    const int tx = threadIdx.x, ty = threadIdx.y;  // block (32, 8)
#pragma unroll
    for (int j = 0; j < 32; j += 8)
        tile[ty + j][tx] = in[(size_t)(by + ty + j) * W + (bx + tx)];
    __syncthreads();
#pragma unroll
    for (int j = 0; j < 32; j += 8)
        out[(size_t)(bx + ty + j) * H + (by + tx)] = tile[tx][ty + j];
}

// ---------------------------------------------------------------------------
// Scatter Hough, zero atomics, 4 px/thread (float4), 2 rows per iteration.
// Lane axis = max(|s|,|c|) axis. Pixel hits bin r iff |u - r| <= hw,
//   u = (i*c + j*s + diag)/step, hw = max(|s|,|c|)/(2*step)
// — algebraically identical to the reference's round() membership.
// Per wave, per slot k (k=0..3): lane u-spacing = 4*lane_co >= 1.38 bins >
// hit window => all active lanes hit DISTINCT bins => non-atomic RMW into the
// wave-private LDS accumulator is race-free (cross-slot RMWs are same-thread,
// in-order on the LDS pipe). Q32 incremental u, f64 refresh per block
// (validated R4-R6: absmax 2.0).
//   waves 0,1 -> row n0+2j ; waves 2,3 -> row n0+2j+1.
// ---------------------------------------------------------------------------
__global__ __launch_bounds__(256) void hough_scatter_k(const float* __restrict__ img,
                                                       const float* __restrict__ imgT,
                                                       float* __restrict__ partial) {
    const int t   = blockIdx.x;            // theta 0..179
    const int n0  = blockIdx.y * RCHUNK;   // sweep-row chunk base
    const int tid = threadIdx.x;
    const int wave = tid >> 6;

    __shared__ float racc[4 * RPAD];       // per-wave private accumulators (12 KB)

    {   // zero accumulators (768 float4)
        float4* z = (float4*)racc;
#pragma unroll
        for (int k = 0; k < 3; ++k)
            z[tid + 256 * k] = make_float4(0.f, 0.f, 0.f, 0.f);
    }
    __syncthreads();

    // ---- per-theta constants (f64, same trig path validated R1-R6) ----
    const double theta = (double)t * (M_PI / 180.0);
    const double s = sin(theta);
    const double c = cos(theta);
    const bool use_x = fabs(s) >= fabs(c);
    const double diag = sqrt(524288.0);          // sqrt(W*W + H*H)
    const double step = (2.0 * diag) / 724.0;    // np.linspace step
    const double inv_step = 1.0 / step;

    const double lane_co = (use_x ? s : c) * inv_step;  // du per pixel (lane axis)
    const double loop_co = (use_x ? c : s) * inv_step;  // du per sweep row
    const double dstep   = diag * inv_step;

    const double SC = 4294967296.0;              // 2^32
    const long long laneq = (long long)rint(lane_co * SC);
    const long long lq    = (long long)rint(loop_co * SC);
    const long long lq2   = 2 * lq;              // u advance per iteration (2 rows)
    const long long L1 = laneq, L2 = 2 * laneq, L3 = 3 * laneq;
    const unsigned hwq = (unsigned)(fabs(lane_co) * 0.5 * SC);
    const unsigned A = 0x80000000u - hwq;        // hit iff lo32 - A <= B
    const unsigned B = 2u * hwq;

    // ---- this thread's 4 lane-axis pixels on row-half h ----
    const int h  = tid >> 7;                     // 0: even rows, 1: odd rows
    const int c0 = (tid & 127) * 4;              // column base
    const double rowpart = (double)(n0 + h) * loop_co + dstep;
    long long u = (long long)rint((rowpart + (double)c0 * lane_co) * SC) + (1ll << 31);

    float* racc_w = racc + wave * RPAD;
    const float* __restrict__ base = use_x ? img : imgT;
    const float4* rowp = (const float4*)(base + (size_t)(n0 + h) * W) + (tid & 127);

#pragma unroll 4
    for (int j = 0; j < RCHUNK / 2; ++j) {
        const float4 v = rowp[j * (2 * W / 4)];
        const long long u0 = u;
        const long long u1 = u + L1;
        const long long u2 = u + L2;
        const long long u3 = u + L3;
        u += lq2;
        if ((unsigned)u0 - A <= B) racc_w[(int)(u0 >> 32)] += v.x;
        if ((unsigned)u1 - A <= B) racc_w[(int)(u1 >> 32)] += v.y;
        if ((unsigned)u2 - A <= B) racc_w[(int)(u2 >> 32)] += v.z;
        if ((unsigned)u3 - A <= B) racc_w[(int)(u3 >> 32)] += v.w;
    }

    __syncthreads();

    // ---- non-atomic flush: partial[chunk][t][r] (coalesced) ----
    float* dst = partial + ((size_t)blockIdx.y * NUM_T + t) * RPAD;
#pragma unroll
    for (int k = 0; k < 3; ++k) {
        const int r = tid + 256 * k;
        dst[r] = racc[r] + racc[RPAD + r] + racc[2 * RPAD + r] + racc[3 * RPAD + r];
    }
}

// ---------------------------------------------------------------------------
// Sum the NCHUNK partials into out[r*NUM_T + t]. Block = one theta.
// ---------------------------------------------------------------------------
__global__ __launch_bounds__(256) void reduce_k(const float* __restrict__ partial,
                                                float* __restrict__ out) {
    const int t = blockIdx.x;
    const int tid = threadIdx.x;
#pragma unroll
    for (int k = 0; k < 3; ++k) {
        const int r = tid + 256 * k;
        if (r < NUM_R) {
            float acc = 0.f;
#pragma unroll
            for (int ch = 0; ch < NCHUNK; ++ch)
                acc += partial[((size_t)ch * NUM_T + t) * RPAD + r];
            out[(size_t)r * NUM_T + t] = acc;
        }
    }
}

// ---------------------------------------------------------------------------
// Fallback (ws too small): R3's pure-gather kernel, no ws, no atomics.
// ---------------------------------------------------------------------------
__global__ __launch_bounds__(256) void hough_gather_k(const float* __restrict__ img,
                                                      float* __restrict__ out) {
    const int t = blockIdx.x;
    const int r = blockIdx.y * 256 + threadIdx.x;
    const int rc = (r < NUM_R) ? r : (NUM_R - 1);

    const double theta = (double)t * (M_PI / 180.0);
    const double s = sin(theta);
    const double c = cos(theta);
    const bool use_x = fabs(s) >= fabs(c);
    double dd = use_x ? s : c;
    if (fabs(dd) < 1e-6) dd = 1.0;
    const double a = use_x ? c : s;
    const double inv = 1.0 / dd;
    const double nk2 = -(a * inv);
    const double diag = sqrt(524288.0);
    const double step = (2.0 * diag) / 724.0;
    double rho = (double)rc * step - diag;
    if (rc == NUM_R - 1) rho = diag;

    const double SCALE = 1099511627776.0;  // 2^40
    const long long NK2q = (long long)rint(nk2 * SCALE);
    long long Y = (long long)rint(rho * inv * SCALE) + (1ll << 39);

    float acc = 0.f;
    if (use_x) {
#pragma unroll 8
        for (int n = 0; n < W; ++n) {
            const int y = (int)(Y >> 40);
            Y += NK2q;
            const float v = img[n * W + min(max(y, 0), W - 1)];
            acc += ((unsigned)y < (unsigned)W) ? v : 0.f;
        }
    } else {
#pragma unroll 4
        for (int n = 0; n < W; ++n) {
            const int y = (int)(Y >> 40);
            Y += NK2q;
            const float v = img[min(max(y, 0), W - 1) * W + n];
            acc += ((unsigned)y < (unsigned)W) ? v : 0.f;
        }
    }
    if (r < NUM_R) out[(size_t)r * NUM_T + t] = acc;
}

extern "C" void kernel_launch(void* const* d_in, const int* in_sizes, int n_in,
                              void* d_out, int out_size, void* d_ws, size_t ws_size,
                              hipStream_t stream) {
    const float* img = (const float*)d_in[0];
    float* out = (float*)d_out;

    if (ws_size >= WS_FLOATS * sizeof(float)) {
        float* imgT = (float*)d_ws;
        float* partial = (float*)d_ws + (size_t)W * H;

        transpose_k<<<dim3(16, 16), dim3(32, 8), 0, stream>>>(img, imgT);
        hough_scatter_k<<<dim3(NUM_T, NCHUNK), dim3(256), 0, stream>>>(img, imgT, partial);
        reduce_k<<<dim3(NUM_T), dim3(256), 0, stream>>>(partial, out);
    } else {
        hough_gather_k<<<dim3(NUM_T, (NUM_R + 255) / 256), dim3(256), 0, stream>>>(img, out);
    }
}